// Round 8
// baseline (78.041 us; speedup 1.0000x reference)
//
#include <hip/hip_runtime.h>
#include <math.h>

// Hexagonal sensor photon binning — R8 (= R7 with compile fix):
//  * clang ext_vector f32x4 instead of HIP float4 so
//    __builtin_nontemporal_load accepts the pointer.
//  * 2-stage software pipeline: issue next iteration's 6 x 16B loads BEFORE
//    processing the current one (vmcnt wait covered by ~1600cy of VALU).
//  * closed-form hex pixel index (no LUT), per-block LDS histogram,
//    partials flush + reduce (absmax was 0.0 for this math).

#define FLUSH_P 64

typedef float f32x4 __attribute__((ext_vector_type(4)));

__global__ void hex_zero_kernel(float* __restrict__ p, int n) {
    int i = blockIdx.x * blockDim.x + threadIdx.x;
    if (i < n) p[i] = 0.0f;
}

__global__ __launch_bounds__(256) void hex_reduce_kernel(
    const float* __restrict__ partials, float* __restrict__ out, int n_pixels)
{
    int pix = blockIdx.x * blockDim.x + threadIdx.x;
    if (pix >= n_pixels) return;
    float s = 0.0f;
    #pragma unroll 8
    for (int j = 0; j < FLUSH_P; ++j) s += partials[j * n_pixels + pix];
    out[pix] = s;
}

__global__ __launch_bounds__(256) void hex_bin_kernel(
    const float* __restrict__ x,
    const float* __restrict__ y,
    const float* __restrict__ vals,
    const float* __restrict__ hex_size_p,
    const float* __restrict__ q_off_p,
    const float* __restrict__ r_off_p,
    const int*   __restrict__ q_min_p,
    const int*   __restrict__ r_min_p,
    int Rh,              // hex radius (24); Q = 2*Rh+1
    int n_pixels, int n_photons,
    float* __restrict__ flush_dst,   // partials (P rows) or out (fallback)
    int use_partials)
{
    extern __shared__ float hist[];  // n_pixels floats
    for (int i = threadIdx.x; i < n_pixels; i += blockDim.x) hist[i] = 0.0f;
    __syncthreads();

    const float inv_h = 1.0f / hex_size_p[0];
    const float qoff  = q_off_p[0];
    const float roff  = r_off_p[0];
    const int   qmin  = q_min_p[0];
    const int   rmin  = r_min_p[0];

    const int   twoR  = 2 * Rh;
    const int   Tbase = (Rh + 1) * Rh + (Rh * (Rh - 1)) / 2;

    const float cq  = 0.57735026918962576f;  // sqrt(3)/3
    const float c3  = 0.33333333333333333f;  // 1/3
    const float c23 = 0.66666666666666667f;  // 2/3

    auto process = [&](float xf, float yf, float vf) {
        float q = (cq * xf - c3 * yf) * inv_h - qoff;
        float r = (c23 * yf) * inv_h - roff;
        float s = -q - r;
        float qr = rintf(q);   // round-half-even == jnp.round
        float rr = rintf(r);
        float sr = rintf(s);
        float qd = fabsf(qr - q);
        float rd = fabsf(rr - r);
        float sd = fabsf(sr - s);
        float q2 = (qd > rd && qd > sd) ? (-rr - sr) : qr;
        float r2 = (rd > qd && rd > sd) ? (-qr - sr) : rr;
        int qi = (int)q2 - qmin;   // exact for integral floats
        int ri = (int)r2 - rmin;
        int d = qi + ri;
        if (qi >= 0 && qi <= twoR && ri >= 0 && ri <= twoR &&
            d >= Rh && d <= 3 * Rh) {
            int p;
            if (qi <= Rh) {
                p = (Rh + 1) * qi + (qi * (qi - 1)) / 2 + (d - Rh);
            } else {
                int u = qi - Rh;
                p = Tbase + (twoR + 1) * u - (u * (u - 1)) / 2 + ri;
            }
            atomicAdd(&hist[p], vf);  // ds_add_f32 (no return)
        }
    };

    const int tid    = blockIdx.x * blockDim.x + threadIdx.x;
    const int stride = gridDim.x * blockDim.x;
    const int n8     = n_photons >> 3;   // groups of 8 photons (2x 16B)

    const f32x4* __restrict__ x4 = (const f32x4*)x;
    const f32x4* __restrict__ y4 = (const f32x4*)y;
    const f32x4* __restrict__ v4 = (const f32x4*)vals;

    // ---- software-pipelined main loop: load(i+stride) before process(i) ----
    f32x4 xa, xb, ya, yb, va, vb;
    int i = tid;
    if (i < n8) {
        int a = 2 * i, b = a + 1;
        xa = __builtin_nontemporal_load(&x4[a]);
        xb = __builtin_nontemporal_load(&x4[b]);
        ya = __builtin_nontemporal_load(&y4[a]);
        yb = __builtin_nontemporal_load(&y4[b]);
        va = __builtin_nontemporal_load(&v4[a]);
        vb = __builtin_nontemporal_load(&v4[b]);
    }
    while (i < n8) {
        int nx = i + stride;
        f32x4 nxa, nxb, nya, nyb, nva, nvb;
        bool has_next = nx < n8;
        if (has_next) {
            int a = 2 * nx, b = a + 1;
            nxa = __builtin_nontemporal_load(&x4[a]);
            nxb = __builtin_nontemporal_load(&x4[b]);
            nya = __builtin_nontemporal_load(&y4[a]);
            nyb = __builtin_nontemporal_load(&y4[b]);
            nva = __builtin_nontemporal_load(&v4[a]);
            nvb = __builtin_nontemporal_load(&v4[b]);
        }
        process(xa.x, ya.x, va.x);
        process(xa.y, ya.y, va.y);
        process(xa.z, ya.z, va.z);
        process(xa.w, ya.w, va.w);
        process(xb.x, yb.x, vb.x);
        process(xb.y, yb.y, vb.y);
        process(xb.z, yb.z, vb.z);
        process(xb.w, yb.w, vb.w);
        if (has_next) {
            xa = nxa; xb = nxb; ya = nya; yb = nyb; va = nva; vb = nvb;
        }
        i = nx;
    }
    // tail (N % 8 != 0)
    for (int t = (n8 << 3) + tid; t < n_photons; t += stride) {
        process(x[t], y[t], vals[t]);
    }

    __syncthreads();
    float* dst = use_partials
        ? flush_dst + (size_t)(blockIdx.x & (FLUSH_P - 1)) * n_pixels
        : flush_dst;
    for (int k = threadIdx.x; k < n_pixels; k += blockDim.x) {
        float h = hist[k];
        if (h != 0.0f) atomicAdd(&dst[k], h);
    }
}

extern "C" void kernel_launch(void* const* d_in, const int* in_sizes, int n_in,
                              void* d_out, int out_size, void* d_ws, size_t ws_size,
                              hipStream_t stream) {
    const float* x      = (const float*)d_in[0];
    const float* y      = (const float*)d_in[1];
    const float* vals   = (const float*)d_in[2];
    const float* hexs   = (const float*)d_in[4];
    const float* qoff   = (const float*)d_in[5];
    const float* roff   = (const float*)d_in[6];
    const int*   qmin   = (const int*)d_in[7];
    const int*   rmin   = (const int*)d_in[8];

    const int n_photons = in_sizes[0];
    const int lut_elems = in_sizes[3];
    const int Q  = (int)(0.5 + sqrt((double)lut_elems));  // 49
    const int Rh = (Q - 1) / 2;                           // 24
    const int n_pixels = out_size;

    float* out = (float*)d_out;
    float* partials = (float*)d_ws;

    const size_t partial_elems = (size_t)FLUSH_P * (size_t)n_pixels;
    const int use_partials = (ws_size >= partial_elems * sizeof(float)) ? 1 : 0;

    const int threads = 256;
    const int blocks  = 2048;   // 8 blocks/CU resident
    const size_t lds_bytes = (size_t)n_pixels * sizeof(float);

    if (use_partials) {
        int zn = (int)partial_elems;
        hex_zero_kernel<<<(zn + 255) / 256, 256, 0, stream>>>(partials, zn);
        hex_bin_kernel<<<blocks, threads, lds_bytes, stream>>>(
            x, y, vals, hexs, qoff, roff, qmin, rmin,
            Rh, n_pixels, n_photons, partials, 1);
        hex_reduce_kernel<<<(n_pixels + 255) / 256, 256, 0, stream>>>(
            partials, out, n_pixels);
    } else {
        hex_zero_kernel<<<(n_pixels + 255) / 256, 256, 0, stream>>>(out, n_pixels);
        hex_bin_kernel<<<blocks, threads, lds_bytes, stream>>>(
            x, y, vals, hexs, qoff, roff, qmin, rmin,
            Rh, n_pixels, n_photons, out, 0);
    }
}